// Round 1
// baseline (489.523 us; speedup 1.0000x reference)
//
#include <hip/hip_runtime.h>
#include <stdint.h>

#define BB   8192
#define DD   1024
#define EE   8
#define RHH  128
#define EHH  256
#define NE1  2048        // E*EH
#define KX   2112        // NE1 + 64 (8 bias cols + 56 zero pad), %64==0

#define BM 128
#define BN 128
#define BK 64

using f32x4  = __attribute__((ext_vector_type(4))) float;
using bf16x8 = __attribute__((ext_vector_type(8))) __bf16;

__device__ __forceinline__ unsigned short f2bf(float f) {
    union { float f; uint32_t u; } v; v.f = f;
    uint32_t u = v.u;
    uint32_t r = (u + 0x7FFFu + ((u >> 16) & 1u)) >> 16;
    return (unsigned short)r;
}
__device__ __forceinline__ float bf2f(unsigned short h) {
    union { uint32_t u; float f; } v; v.u = ((uint32_t)h) << 16;
    return v.f;
}

__device__ __forceinline__ void llds16(void* l, const void* g) {
    __builtin_amdgcn_global_load_lds(
        (const __attribute__((address_space(1))) uint32_t*)g,
        (__attribute__((address_space(3))) uint32_t*)l, 16, 0, 0);
}

// ---------------- conversion / prep kernels ----------------

__global__ __launch_bounds__(256) void cvt_x(const float* __restrict__ in,
                                             unsigned short* __restrict__ out) {
    int i = (blockIdx.x * 256 + threadIdx.x) * 4;   // total B*D = 8388608
    f32x4 v = *(const f32x4*)(in + i);
    out[i + 0] = f2bf(v.x);
    out[i + 1] = f2bf(v.y);
    out[i + 2] = f2bf(v.z);
    out[i + 3] = f2bf(v.w);
}

// rw1t[h][d] = rw1[d][h]   (128 x 1024)
__global__ __launch_bounds__(256) void prep_rw1(const float* __restrict__ src,
                                                unsigned short* __restrict__ dst) {
    int o = blockIdx.x * 256 + threadIdx.x;         // 131072
    int h = o >> 10, d = o & 1023;
    dst[o] = f2bf(src[d * RHH + h]);
}

// W1t[n][k] = ew1[e][k][h], n = e*256+h   (2048 x 1024)
__global__ __launch_bounds__(256) void prep_w1(const float* __restrict__ src,
                                               unsigned short* __restrict__ dst) {
    int o = blockIdx.x * 256 + threadIdx.x;         // 2097152
    int n = o >> 10, k = o & 1023;
    int e = n >> 8, h = n & 255;
    dst[o] = f2bf(src[((e << 10) + k) * 256 + h]);
}

// W2t[d][np]: np<2048 -> ew2[e][h][d] (np=e*256+h); np in [2048,2056) -> eb2[np-2048][d]; else 0
__global__ __launch_bounds__(256) void prep_w2(const float* __restrict__ w2,
                                               const float* __restrict__ b2,
                                               unsigned short* __restrict__ dst) {
    int o = blockIdx.x * 256 + threadIdx.x;         // 1024*2112 = 2162688
    int d = o / KX;
    int np = o - d * KX;
    float v;
    if (np < NE1)            v = w2[np * DD + d];
    else if (np < NE1 + EE)  v = b2[(np - NE1) * DD + d];
    else                     v = 0.0f;
    dst[o] = f2bf(v);
}

// Hb[b][2048+j] = (j<8) ? w[b][j] : 0
__global__ __launch_bounds__(256) void fill_wcols(const float* __restrict__ wbuf,
                                                  unsigned short* __restrict__ Hb) {
    int idx = blockIdx.x * 256 + threadIdx.x;       // B*64 = 524288
    int b = idx >> 6, j = idx & 63;
    float v = (j < EE) ? wbuf[b * EE + j] : 0.0f;
    Hb[(size_t)b * KX + NE1 + j] = f2bf(v);
}

// router level-2: logits = rh @ rw2 + rb2 ; softmax over 8 experts
__global__ __launch_bounds__(256) void router2(const unsigned short* __restrict__ rh,
                                               const float* __restrict__ rw2,
                                               const float* __restrict__ rb2,
                                               float* __restrict__ wout) {
    __shared__ float lw2[RHH * EE];
    __shared__ float lb2[EE];
    int tid = threadIdx.x;
    for (int i = tid; i < RHH * EE; i += 256) lw2[i] = rw2[i];
    if (tid < EE) lb2[tid] = rb2[tid];
    __syncthreads();

    int row = blockIdx.x * 32 + (tid >> 3);
    int e   = tid & 7;
    const unsigned short* rr = rh + (size_t)row * RHH;
    float acc = lb2[e];
    for (int h = 0; h < RHH; ++h)
        acc += bf2f(rr[h]) * lw2[h * EE + e];

    float m = acc;
    for (int off = 1; off < 8; off <<= 1)
        m = fmaxf(m, __shfl_xor(m, off, 8));
    float p = expf(acc - m);
    float s = p;
    for (int off = 1; off < 8; off <<= 1)
        s += __shfl_xor(s, off, 8);
    wout[(size_t)row * EE + e] = p / s;
}

// ---------------- main GEMM: C[M,N] = A[M,K] * Bt[N,K]^T ----------------
// EPI 0: bf16( relu(acc + bias[n]) )
// EPI 1: bf16( relu(acc + bias[n]) * wrow[m][n>>8] )
// EPI 2: bf16( acc )
// EPI 3: f32 ( acc )
template<int EPI>
__global__ __launch_bounds__(256)
void gemm_bt(const unsigned short* __restrict__ A, const unsigned short* __restrict__ Bt,
             void* __restrict__ C, const float* __restrict__ bias,
             const float* __restrict__ wrow,
             int M, int N, int K, int lda, int ldb, int ldc)
{
    __shared__ __align__(16) unsigned short As[BM * BK];
    __shared__ __align__(16) unsigned short Bs[BN * BK];

    const int tid  = threadIdx.x;
    const int lane = tid & 63;
    const int wave = tid >> 6;
    const int wm   = (wave >> 1) << 6;
    const int wn   = (wave & 1) << 6;
    const int l16  = lane & 15;
    const int lhi  = lane >> 4;

    const long bm0 = (long)blockIdx.x * BM;
    const long bn0 = (long)blockIdx.y * BN;

    const char* aBase = (const char*)(A + bm0 * lda);
    const char* bBase = (const char*)(Bt + bn0 * ldb);

    const char* asrc[4];
    const char* bsrc[4];
#pragma unroll
    for (int r = 0; r < 4; ++r) {
        int o = r * 4096 + tid * 16;                 // byte offset in 16KB tile
        asrc[r] = aBase + (long)(o >> 7) * (long)(lda * 2) + (o & 127);
        bsrc[r] = bBase + (long)(o >> 7) * (long)(ldb * 2) + (o & 127);
    }

    f32x4 acc[4][4];
    const f32x4 zero = {0.f, 0.f, 0.f, 0.f};
#pragma unroll
    for (int i = 0; i < 4; ++i)
#pragma unroll
        for (int j = 0; j < 4; ++j)
            acc[i][j] = zero;

    const int kiters = K / BK;
    for (int it = 0; it < kiters; ++it) {
        __syncthreads();                             // prev compute done before overwrite
#pragma unroll
        for (int r = 0; r < 4; ++r) {
            llds16((char*)As + r * 4096 + tid * 16, asrc[r]);
            llds16((char*)Bs + r * 4096 + tid * 16, bsrc[r]);
            asrc[r] += BK * 2;
            bsrc[r] += BK * 2;
        }
        __syncthreads();                             // loads drained (vmcnt(0) at barrier)

#pragma unroll
        for (int kk = 0; kk < BK; kk += 32) {
            bf16x8 af[4], bfr[4];
#pragma unroll
            for (int mi = 0; mi < 4; ++mi)
                af[mi] = *(const bf16x8*)(As + (wm + mi * 16 + l16) * BK + kk + lhi * 8);
#pragma unroll
            for (int ni = 0; ni < 4; ++ni)
                bfr[ni] = *(const bf16x8*)(Bs + (wn + ni * 16 + l16) * BK + kk + lhi * 8);
#pragma unroll
            for (int mi = 0; mi < 4; ++mi)
#pragma unroll
                for (int ni = 0; ni < 4; ++ni)
                    acc[mi][ni] = __builtin_amdgcn_mfma_f32_16x16x32_bf16(
                        af[mi], bfr[ni], acc[mi][ni], 0, 0, 0);
        }
    }

    // epilogue: D element (m,n): m = lhi*4 + reg (fragment row), n = l16 (fragment col)
#pragma unroll
    for (int mi = 0; mi < 4; ++mi) {
#pragma unroll
        for (int ni = 0; ni < 4; ++ni) {
            const long gn = bn0 + wn + ni * 16 + l16;
            float bv = 0.f;
            if (EPI == 0 || EPI == 1) bv = bias[gn];
#pragma unroll
            for (int r = 0; r < 4; ++r) {
                const long gm = bm0 + wm + mi * 16 + lhi * 4 + r;
                float v = acc[mi][ni][r];
                if (EPI == 0) {
                    v = fmaxf(v + bv, 0.f);
                    ((unsigned short*)C)[gm * ldc + gn] = f2bf(v);
                } else if (EPI == 1) {
                    v = fmaxf(v + bv, 0.f) * wrow[gm * 8 + (int)(gn >> 8)];
                    ((unsigned short*)C)[gm * ldc + gn] = f2bf(v);
                } else if (EPI == 2) {
                    ((unsigned short*)C)[gm * ldc + gn] = f2bf(v);
                } else {
                    ((float*)C)[gm * ldc + gn] = v;
                }
            }
        }
    }
}

// ---------------- launch ----------------

extern "C" void kernel_launch(void* const* d_in, const int* in_sizes, int n_in,
                              void* d_out, int out_size, void* d_ws, size_t ws_size,
                              hipStream_t stream) {
    (void)in_sizes; (void)n_in; (void)out_size; (void)ws_size;
    const float* x   = (const float*)d_in[0];
    const float* rw1 = (const float*)d_in[1];
    const float* rb1 = (const float*)d_in[2];
    const float* rw2 = (const float*)d_in[3];
    const float* rb2 = (const float*)d_in[4];
    const float* ew1 = (const float*)d_in[5];
    const float* eb1 = (const float*)d_in[6];
    const float* ew2 = (const float*)d_in[7];
    const float* eb2 = (const float*)d_in[8];

    char* ws = (char*)d_ws;
    unsigned short* xb   = (unsigned short*)(ws);                 // 16,777,216 B
    unsigned short* rh   = (unsigned short*)(ws + 16777216);      //  2,097,152 B
    float*          wbuf = (float*)         (ws + 18874368);      //    262,144 B
    unsigned short* Hb   = (unsigned short*)(ws + 19136512);      // 34,603,008 B
    unsigned short* rw1t = (unsigned short*)(ws + 53739520);      //    262,144 B
    unsigned short* W1t  = (unsigned short*)(ws + 54001664);      //  4,194,304 B
    unsigned short* W2t  = (unsigned short*)(ws + 58195968);      //  4,325,376 B
    // total 62,521,344 B

    cvt_x<<<8192, 256, 0, stream>>>(x, xb);

    for (int l = 0; l < 3; ++l) {
        prep_rw1<<<512, 256, 0, stream>>>(rw1 + (size_t)l * DD * RHH, rw1t);
        prep_w1 <<<8192, 256, 0, stream>>>(ew1 + (size_t)l * EE * DD * EHH, W1t);
        prep_w2 <<<8448, 256, 0, stream>>>(ew2 + (size_t)l * EE * EHH * DD,
                                           eb2 + (size_t)l * EE * DD, W2t);

        // router hidden: rh = relu(x @ rw1 + rb1)  [8192,128]
        gemm_bt<0><<<dim3(64, 1), 256, 0, stream>>>(xb, rw1t, rh,
                                                    rb1 + l * RHH, nullptr,
                                                    BB, RHH, DD, DD, DD, RHH);
        // softmax router weights
        router2<<<256, 256, 0, stream>>>(rh, rw2 + (size_t)l * RHH * EE,
                                         rb2 + l * EE, wbuf);
        // append w columns (+zero pad) to Hb
        fill_wcols<<<2048, 256, 0, stream>>>(wbuf, Hb);
        // H' = relu(x @ W1 + b1) * w   [8192, 2048] (stride 2112)
        gemm_bt<1><<<dim3(64, 16), 256, 0, stream>>>(xb, W1t, Hb,
                                                     eb1 + (size_t)l * NE1, wbuf,
                                                     BB, NE1, DD, DD, DD, KX);
        // out = H' @ W2ext   (bias folded via K-extension)
        if (l < 2)
            gemm_bt<2><<<dim3(64, 8), 256, 0, stream>>>(Hb, W2t, xb, nullptr, nullptr,
                                                        BB, DD, KX, KX, KX, DD);
        else
            gemm_bt<3><<<dim3(64, 8), 256, 0, stream>>>(Hb, W2t, d_out, nullptr, nullptr,
                                                        BB, DD, KX, KX, KX, DD);
    }
}

// Round 2
// 446.440 us; speedup vs baseline: 1.0965x; 1.0965x over previous
//
#include <hip/hip_runtime.h>
#include <stdint.h>

#define BB   8192
#define DD   1024
#define EE   8
#define RHH  128
#define EHH  256
#define NE1  2048        // E*EH
#define KX   2112        // NE1 + 64 (8 bias cols + 56 zero pad), %64==0

// old-style 128x128 kernel kept for the router-hidden GEMM only
#define BM 128
#define BN 128
#define BK 64

using f32x4  = __attribute__((ext_vector_type(4))) float;
using bf16x8 = __attribute__((ext_vector_type(8))) __bf16;

__device__ __forceinline__ unsigned short f2bf(float f) {
    union { float f; uint32_t u; } v; v.f = f;
    uint32_t u = v.u;
    uint32_t r = (u + 0x7FFFu + ((u >> 16) & 1u)) >> 16;
    return (unsigned short)r;
}
__device__ __forceinline__ float bf2f(unsigned short h) {
    union { uint32_t u; float f; } v; v.u = ((uint32_t)h) << 16;
    return v.f;
}

__device__ __forceinline__ void llds16(void* l, const void* g) {
    __builtin_amdgcn_global_load_lds(
        (const __attribute__((address_space(1))) uint32_t*)g,
        (__attribute__((address_space(3))) uint32_t*)l, 16, 0, 0);
}

__device__ __forceinline__ void rawbar() {
    asm volatile("" ::: "memory");
    __builtin_amdgcn_s_barrier();
    asm volatile("" ::: "memory");
}

// ---------------- conversion / prep kernels ----------------

__global__ __launch_bounds__(256) void cvt_x(const float* __restrict__ in,
                                             unsigned short* __restrict__ out) {
    int i = (blockIdx.x * 256 + threadIdx.x) * 4;   // total B*D = 8388608
    f32x4 v = *(const f32x4*)(in + i);
    out[i + 0] = f2bf(v.x);
    out[i + 1] = f2bf(v.y);
    out[i + 2] = f2bf(v.z);
    out[i + 3] = f2bf(v.w);
}

// rw1t[h][d] = rw1[d][h]   (128 x 1024)
__global__ __launch_bounds__(256) void prep_rw1(const float* __restrict__ src,
                                                unsigned short* __restrict__ dst) {
    int o = blockIdx.x * 256 + threadIdx.x;         // 131072
    int h = o >> 10, d = o & 1023;
    dst[o] = f2bf(src[d * RHH + h]);
}

// W1t[n][k] = ew1[e][k][h], n = e*256+h   (2048 x 1024)
__global__ __launch_bounds__(256) void prep_w1(const float* __restrict__ src,
                                               unsigned short* __restrict__ dst) {
    int o = blockIdx.x * 256 + threadIdx.x;         // 2097152
    int n = o >> 10, k = o & 1023;
    int e = n >> 8, h = n & 255;
    dst[o] = f2bf(src[((e << 10) + k) * 256 + h]);
}

// W2t[d][np]: np<2048 -> ew2[e][h][d] (np=e*256+h); np in [2048,2056) -> eb2[np-2048][d]; else 0
__global__ __launch_bounds__(256) void prep_w2(const float* __restrict__ w2,
                                               const float* __restrict__ b2,
                                               unsigned short* __restrict__ dst) {
    int o = blockIdx.x * 256 + threadIdx.x;         // 1024*2112 = 2162688
    int d = o / KX;
    int np = o - d * KX;
    float v;
    if (np < NE1)            v = w2[np * DD + d];
    else if (np < NE1 + EE)  v = b2[(np - NE1) * DD + d];
    else                     v = 0.0f;
    dst[o] = f2bf(v);
}

// Hb[b][2048+j] = (j<8) ? w[b][j] : 0
__global__ __launch_bounds__(256) void fill_wcols(const float* __restrict__ wbuf,
                                                  unsigned short* __restrict__ Hb) {
    int idx = blockIdx.x * 256 + threadIdx.x;       // B*64 = 524288
    int b = idx >> 6, j = idx & 63;
    float v = (j < EE) ? wbuf[b * EE + j] : 0.0f;
    Hb[(size_t)b * KX + NE1 + j] = f2bf(v);
}

// router level-2: logits = rh @ rw2 + rb2 ; softmax over 8 experts
__global__ __launch_bounds__(256) void router2(const unsigned short* __restrict__ rh,
                                               const float* __restrict__ rw2,
                                               const float* __restrict__ rb2,
                                               float* __restrict__ wout) {
    __shared__ float lw2[RHH * EE];
    __shared__ float lb2[EE];
    int tid = threadIdx.x;
    for (int i = tid; i < RHH * EE; i += 256) lw2[i] = rw2[i];
    if (tid < EE) lb2[tid] = rb2[tid];
    __syncthreads();

    int row = blockIdx.x * 32 + (tid >> 3);
    int e   = tid & 7;
    const unsigned short* rr = rh + (size_t)row * RHH;
    float acc = lb2[e];
    for (int h = 0; h < RHH; ++h)
        acc += bf2f(rr[h]) * lw2[h * EE + e];

    float m = acc;
    for (int off = 1; off < 8; off <<= 1)
        m = fmaxf(m, __shfl_xor(m, off, 8));
    float p = expf(acc - m);
    float s = p;
    for (int off = 1; off < 8; off <<= 1)
        s += __shfl_xor(s, off, 8);
    wout[(size_t)row * EE + e] = p / s;
}

// ---------------- old 128x128 GEMM (router-hidden only, EPI 0) ----------------
__global__ __launch_bounds__(256)
void gemm_bt(const unsigned short* __restrict__ A, const unsigned short* __restrict__ Bt,
             void* __restrict__ C, const float* __restrict__ bias,
             int M, int N, int K, int lda, int ldb, int ldc)
{
    __shared__ __align__(16) unsigned short As[BM * BK];
    __shared__ __align__(16) unsigned short Bs[BN * BK];

    const int tid  = threadIdx.x;
    const int lane = tid & 63;
    const int wave = tid >> 6;
    const int wm   = (wave >> 1) << 6;
    const int wn   = (wave & 1) << 6;
    const int l16  = lane & 15;
    const int lhi  = lane >> 4;

    const long bm0 = (long)blockIdx.x * BM;
    const long bn0 = (long)blockIdx.y * BN;

    const char* aBase = (const char*)(A + bm0 * lda);
    const char* bBase = (const char*)(Bt + bn0 * ldb);

    const char* asrc[4];
    const char* bsrc[4];
#pragma unroll
    for (int r = 0; r < 4; ++r) {
        int o = r * 4096 + tid * 16;
        asrc[r] = aBase + (long)(o >> 7) * (long)(lda * 2) + (o & 127);
        bsrc[r] = bBase + (long)(o >> 7) * (long)(ldb * 2) + (o & 127);
    }

    f32x4 acc[4][4];
    const f32x4 zero = {0.f, 0.f, 0.f, 0.f};
#pragma unroll
    for (int i = 0; i < 4; ++i)
#pragma unroll
        for (int j = 0; j < 4; ++j)
            acc[i][j] = zero;

    const int kiters = K / BK;
    for (int it = 0; it < kiters; ++it) {
        __syncthreads();
#pragma unroll
        for (int r = 0; r < 4; ++r) {
            llds16((char*)As + r * 4096 + tid * 16, asrc[r]);
            llds16((char*)Bs + r * 4096 + tid * 16, bsrc[r]);
            asrc[r] += BK * 2;
            bsrc[r] += BK * 2;
        }
        __syncthreads();

#pragma unroll
        for (int kk = 0; kk < BK; kk += 32) {
            bf16x8 af[4], bfr[4];
#pragma unroll
            for (int mi = 0; mi < 4; ++mi)
                af[mi] = *(const bf16x8*)(As + (wm + mi * 16 + l16) * BK + kk + lhi * 8);
#pragma unroll
            for (int ni = 0; ni < 4; ++ni)
                bfr[ni] = *(const bf16x8*)(Bs + (wn + ni * 16 + l16) * BK + kk + lhi * 8);
#pragma unroll
            for (int mi = 0; mi < 4; ++mi)
#pragma unroll
                for (int ni = 0; ni < 4; ++ni)
                    acc[mi][ni] = __builtin_amdgcn_mfma_f32_16x16x32_bf16(
                        af[mi], bfr[ni], acc[mi][ni], 0, 0, 0);
        }
    }

#pragma unroll
    for (int mi = 0; mi < 4; ++mi) {
#pragma unroll
        for (int ni = 0; ni < 4; ++ni) {
            const long gn = bn0 + wn + ni * 16 + l16;
            float bv = bias[gn];
#pragma unroll
            for (int r = 0; r < 4; ++r) {
                const long gm = bm0 + wm + mi * 16 + lhi * 4 + r;
                float v = fmaxf(acc[mi][ni][r] + bv, 0.f);
                ((unsigned short*)C)[gm * ldc + gn] = f2bf(v);
            }
        }
    }
}

// ---------------- pipelined 256xBN GEMM, counted vmcnt, swizzled LDS ----------------
// C[M,N] = A[M,K] * Bt[N,K]^T.  BM=256 fixed, BKt=32, 512 threads = 8 waves (2M x 4N).
// LDS: Asl 2x16KB, Bsl 2x(BNv*64B). XOR swizzle: col16 ^= (row>>1)&3 (within 64B rows),
// applied to BOTH global_load_lds source addresses and ds_read addresses (involution).
// Pipeline ledger (per wave, issue order ... A(t),B(t),A(t+1),B(t+1),...):
//   boundary of iter t: issue A(t+1)[2 loads]; vmcnt(2) -> all but newest 2 done
//     => A(t),B(t) landed. barrier => landed for ALL waves, and all waves finished
//     reading tile t-1 (their last reads precede the barriers they crossed).
//   SP1: ds_read aF(x8)+bF(half0); issue B(t+1); prio1; MFMA x16; prio0; barrier
//   SP2: ds_read bF(half1); prio1; MFMA x16; prio0
// Loads for tile t+1 stay in flight across both barriers (never drain in steady state).
// EPI 1: bf16( relu(acc+bias[n]) * wrow[m][n>>8] ) ; EPI 2: bf16(acc) ; EPI 3: f32(acc)
template<int BNv, int EPI>
__global__ __launch_bounds__(512, 2)
void gemm8p(const unsigned short* __restrict__ A, const unsigned short* __restrict__ Bt,
            void* __restrict__ C, const float* __restrict__ bias,
            const float* __restrict__ wrow,
            int K, int lda, int ldb, int ldc)
{
    constexpr int NCW = BNv / 4;     // per-wave cols (64 or 32)
    constexpr int NI  = NCW / 16;    // acc cols (4 or 2)
    constexpr int NIH = NI / 2;      // per-half (2 or 1)
    constexpr int LB  = BNv / 128;   // B loads/thread/tile (2 or 1)

    __shared__ __align__(16) unsigned short Asl[2][256 * 32];
    __shared__ __align__(16) unsigned short Bsl[2][BNv * 32];

    const int tid  = threadIdx.x;
    const int lane = tid & 63;
    const int wv   = tid >> 6;
    const int wr   = wv >> 2;        // 0..1
    const int wc   = wv & 3;         // 0..3
    const int l16  = lane & 15;
    const int lhi  = lane >> 4;

    const long bm0 = (long)blockIdx.x * 256;
    const long bn0 = (long)blockIdx.y * BNv;

    // staging source pointers (pre-swizzled global addresses)
    const int r4  = tid >> 2;                        // 0..127
    const int swc = (tid & 3) ^ ((r4 >> 1) & 3);     // swizzled 16B-slot within 64B
    const char* agp0 = (const char*)A + (bm0 + r4)       * (long)lda * 2 + swc * 16;
    const char* agp1 = (const char*)A + (bm0 + 128 + r4) * (long)lda * 2 + swc * 16;
    const char* bgp0 = (const char*)Bt + (bn0 + r4)      * (long)ldb * 2 + swc * 16;
    const char* bgp1 = (const char*)Bt + (bn0 + ((LB == 2) ? 128 : 0) + r4) * (long)ldb * 2 + swc * 16;

    // ds_read bases (ushort index); swizzle slot uses (row>>1)&3 == (l16>>1)&3 here
    const int swzu = (lhi ^ ((l16 >> 1) & 3)) << 3;            // ushorts (16B = 8)
    const int aidx = (wr * 128 + l16) * 32 + swzu;
    const int bidx = (wc * NCW + l16) * 32 + swzu;

    f32x4 acc[8][NI];
    const f32x4 zero = {0.f, 0.f, 0.f, 0.f};
#pragma unroll
    for (int i = 0; i < 8; ++i)
#pragma unroll
        for (int j = 0; j < NI; ++j)
            acc[i][j] = zero;

    auto stageA = [&](int c) {
        char* d = (char*)(&Asl[c][0]) + tid * 16;
        llds16(d, agp0);
        llds16(d + 8192, agp1);
        agp0 += 64; agp1 += 64;
    };
    auto stageB = [&](int c) {
        char* d = (char*)(&Bsl[c][0]) + tid * 16;
        llds16(d, bgp0);
        bgp0 += 64;
        if constexpr (LB == 2) {
            llds16(d + 8192, bgp1);
            bgp1 += 64;
        }
    };

    const int nt = K / 32;
    stageA(0);
    stageB(0);
    int cur = 0;
    for (int t = 0; t < nt; ++t) {
        const int nxt = cur ^ 1;
        if (t + 1 < nt) {
            stageA(nxt);
            asm volatile("s_waitcnt vmcnt(2)" ::: "memory");  // tile t landed; t+1 in flight
        } else {
            asm volatile("s_waitcnt vmcnt(0)" ::: "memory");  // tail drain (once)
        }
        rawbar();

        bf16x8 aF[8], bF0[NIH];
#pragma unroll
        for (int mi = 0; mi < 8; ++mi)
            aF[mi] = *(const bf16x8*)&Asl[cur][aidx + mi * 512];
#pragma unroll
        for (int ni = 0; ni < NIH; ++ni)
            bF0[ni] = *(const bf16x8*)&Bsl[cur][bidx + ni * 512];
        if (t + 1 < nt) stageB(nxt);

        __builtin_amdgcn_s_setprio(1);
#pragma unroll
        for (int mi = 0; mi < 8; ++mi)
#pragma unroll
            for (int ni = 0; ni < NIH; ++ni)
                acc[mi][ni] = __builtin_amdgcn_mfma_f32_16x16x32_bf16(
                    aF[mi], bF0[ni], acc[mi][ni], 0, 0, 0);
        __builtin_amdgcn_s_setprio(0);

        rawbar();

        bf16x8 bF1[NIH];
#pragma unroll
        for (int ni = 0; ni < NIH; ++ni)
            bF1[ni] = *(const bf16x8*)&Bsl[cur][bidx + (NIH + ni) * 512];

        __builtin_amdgcn_s_setprio(1);
#pragma unroll
        for (int mi = 0; mi < 8; ++mi)
#pragma unroll
            for (int ni = 0; ni < NIH; ++ni)
                acc[mi][NIH + ni] = __builtin_amdgcn_mfma_f32_16x16x32_bf16(
                    aF[mi], bF1[ni], acc[mi][NIH + ni], 0, 0, 0);
        __builtin_amdgcn_s_setprio(0);
        cur = nxt;
    }

    // epilogue
#pragma unroll
    for (int mi = 0; mi < 8; ++mi) {
#pragma unroll
        for (int ni = 0; ni < NI; ++ni) {
            const long gn = bn0 + wc * NCW + ni * 16 + l16;
            float bv = 0.f;
            if (EPI == 1) bv = bias[gn];
#pragma unroll
            for (int r = 0; r < 4; ++r) {
                const long gm = bm0 + wr * 128 + mi * 16 + lhi * 4 + r;
                float v = acc[mi][ni][r];
                if (EPI == 1) {
                    v = fmaxf(v + bv, 0.f) * wrow[gm * 8 + (int)(gn >> 8)];
                    ((unsigned short*)C)[gm * (long)ldc + gn] = f2bf(v);
                } else if (EPI == 2) {
                    ((unsigned short*)C)[gm * (long)ldc + gn] = f2bf(v);
                } else {
                    ((float*)C)[gm * (long)ldc + gn] = v;
                }
            }
        }
    }
}

// ---------------- launch ----------------

extern "C" void kernel_launch(void* const* d_in, const int* in_sizes, int n_in,
                              void* d_out, int out_size, void* d_ws, size_t ws_size,
                              hipStream_t stream) {
    (void)in_sizes; (void)n_in; (void)out_size; (void)ws_size;
    const float* x   = (const float*)d_in[0];
    const float* rw1 = (const float*)d_in[1];
    const float* rb1 = (const float*)d_in[2];
    const float* rw2 = (const float*)d_in[3];
    const float* rb2 = (const float*)d_in[4];
    const float* ew1 = (const float*)d_in[5];
    const float* eb1 = (const float*)d_in[6];
    const float* ew2 = (const float*)d_in[7];
    const float* eb2 = (const float*)d_in[8];

    char* ws = (char*)d_ws;
    unsigned short* xb   = (unsigned short*)(ws);                 // 16,777,216 B
    unsigned short* rh   = (unsigned short*)(ws + 16777216);      //  2,097,152 B
    float*          wbuf = (float*)         (ws + 18874368);      //    262,144 B
    unsigned short* Hb   = (unsigned short*)(ws + 19136512);      // 34,603,008 B
    unsigned short* rw1t = (unsigned short*)(ws + 53739520);      //    262,144 B
    unsigned short* W1t  = (unsigned short*)(ws + 54001664);      //  4,194,304 B
    unsigned short* W2t  = (unsigned short*)(ws + 58195968);      //  4,325,376 B

    cvt_x<<<8192, 256, 0, stream>>>(x, xb);

    for (int l = 0; l < 3; ++l) {
        prep_rw1<<<512, 256, 0, stream>>>(rw1 + (size_t)l * DD * RHH, rw1t);
        prep_w1 <<<8192, 256, 0, stream>>>(ew1 + (size_t)l * EE * DD * EHH, W1t);
        prep_w2 <<<8448, 256, 0, stream>>>(ew2 + (size_t)l * EE * EHH * DD,
                                           eb2 + (size_t)l * EE * DD, W2t);

        // router hidden: rh = relu(x @ rw1 + rb1)  [8192,128]
        gemm_bt<<<dim3(64, 1), 256, 0, stream>>>(xb, rw1t, rh,
                                                 rb1 + l * RHH,
                                                 BB, RHH, DD, DD, DD, RHH);
        // softmax router weights
        router2<<<256, 256, 0, stream>>>(rh, rw2 + (size_t)l * RHH * EE,
                                         rb2 + l * EE, wbuf);
        // append w columns (+zero pad) to Hb
        fill_wcols<<<2048, 256, 0, stream>>>(wbuf, Hb);
        // H' = relu(x @ W1 + b1) * w   [8192, 2048] (stride 2112)
        gemm8p<256, 1><<<dim3(32, 8), 512, 0, stream>>>(xb, W1t, Hb,
                                                        eb1 + (size_t)l * NE1, wbuf,
                                                        DD, DD, DD, KX);
        // out = H' @ W2ext   (bias folded via K-extension)
        if (l < 2)
            gemm8p<128, 2><<<dim3(32, 8), 512, 0, stream>>>(Hb, W2t, xb, nullptr, nullptr,
                                                            KX, KX, KX, DD);
        else
            gemm8p<128, 3><<<dim3(32, 8), 512, 0, stream>>>(Hb, W2t, d_out, nullptr, nullptr,
                                                            KX, KX, KX, DD);
    }
}

// Round 3
// 405.368 us; speedup vs baseline: 1.2076x; 1.1013x over previous
//
#include <hip/hip_runtime.h>
#include <stdint.h>

#define BB   8192
#define DD   1024
#define EE   8
#define RHH  128
#define EHH  256
#define NE1  2048        // E*EH
#define KX   2112        // NE1 + 64 (8 bias cols + 56 zero pad), %64==0

// old-style 128x128 kernel kept for the router-hidden GEMM only
#define BM 128
#define BN 128
#define BK 64

using f32x4  = __attribute__((ext_vector_type(4))) float;
using bf16x8 = __attribute__((ext_vector_type(8))) __bf16;

__device__ __forceinline__ unsigned short f2bf(float f) {
    union { float f; uint32_t u; } v; v.f = f;
    uint32_t u = v.u;
    uint32_t r = (u + 0x7FFFu + ((u >> 16) & 1u)) >> 16;
    return (unsigned short)r;
}
__device__ __forceinline__ float bf2f(unsigned short h) {
    union { uint32_t u; float f; } v; v.u = ((uint32_t)h) << 16;
    return v.f;
}

__device__ __forceinline__ void llds16(void* l, const void* g) {
    __builtin_amdgcn_global_load_lds(
        (const __attribute__((address_space(1))) uint32_t*)g,
        (__attribute__((address_space(3))) uint32_t*)l, 16, 0, 0);
}

__device__ __forceinline__ void rawbar() {
    asm volatile("" ::: "memory");
    __builtin_amdgcn_s_barrier();
    asm volatile("" ::: "memory");
}

// ---------------- conversion / prep kernels ----------------

__global__ __launch_bounds__(256) void cvt_x(const float* __restrict__ in,
                                             unsigned short* __restrict__ out) {
    int i = (blockIdx.x * 256 + threadIdx.x) * 4;   // total B*D = 8388608
    f32x4 v = *(const f32x4*)(in + i);
    out[i + 0] = f2bf(v.x);
    out[i + 1] = f2bf(v.y);
    out[i + 2] = f2bf(v.z);
    out[i + 3] = f2bf(v.w);
}

// rw1t[h][d] = rw1[d][h]   (128 x 1024)
__global__ __launch_bounds__(256) void prep_rw1(const float* __restrict__ src,
                                                unsigned short* __restrict__ dst) {
    int o = blockIdx.x * 256 + threadIdx.x;         // 131072
    int h = o >> 10, d = o & 1023;
    dst[o] = f2bf(src[d * RHH + h]);
}

// W1t[n][k] = ew1[e][k][h], n = e*256+h   (2048 x 1024)
__global__ __launch_bounds__(256) void prep_w1(const float* __restrict__ src,
                                               unsigned short* __restrict__ dst) {
    int o = blockIdx.x * 256 + threadIdx.x;         // 2097152
    int n = o >> 10, k = o & 1023;
    int e = n >> 8, h = n & 255;
    dst[o] = f2bf(src[((e << 10) + k) * 256 + h]);
}

// W2t[d][np]: np<2048 -> ew2[e][h][d] (np=e*256+h); np in [2048,2056) -> eb2[np-2048][d]; else 0
__global__ __launch_bounds__(256) void prep_w2(const float* __restrict__ w2,
                                               const float* __restrict__ b2,
                                               unsigned short* __restrict__ dst) {
    int o = blockIdx.x * 256 + threadIdx.x;         // 1024*2112 = 2162688
    int d = o / KX;
    int np = o - d * KX;
    float v;
    if (np < NE1)            v = w2[np * DD + d];
    else if (np < NE1 + EE)  v = b2[(np - NE1) * DD + d];
    else                     v = 0.0f;
    dst[o] = f2bf(v);
}

// Hb[b][2048+j] = (j<8) ? w[b][j] : 0
__global__ __launch_bounds__(256) void fill_wcols(const float* __restrict__ wbuf,
                                                  unsigned short* __restrict__ Hb) {
    int idx = blockIdx.x * 256 + threadIdx.x;       // B*64 = 524288
    int b = idx >> 6, j = idx & 63;
    float v = (j < EE) ? wbuf[b * EE + j] : 0.0f;
    Hb[(size_t)b * KX + NE1 + j] = f2bf(v);
}

// router level-2: logits = rh @ rw2 + rb2 ; softmax over 8 experts
__global__ __launch_bounds__(256) void router2(const unsigned short* __restrict__ rh,
                                               const float* __restrict__ rw2,
                                               const float* __restrict__ rb2,
                                               float* __restrict__ wout) {
    __shared__ float lw2[RHH * EE];
    __shared__ float lb2[EE];
    int tid = threadIdx.x;
    for (int i = tid; i < RHH * EE; i += 256) lw2[i] = rw2[i];
    if (tid < EE) lb2[tid] = rb2[tid];
    __syncthreads();

    int row = blockIdx.x * 32 + (tid >> 3);
    int e   = tid & 7;
    const unsigned short* rr = rh + (size_t)row * RHH;
    float acc = lb2[e];
    for (int h = 0; h < RHH; ++h)
        acc += bf2f(rr[h]) * lw2[h * EE + e];

    float m = acc;
    for (int off = 1; off < 8; off <<= 1)
        m = fmaxf(m, __shfl_xor(m, off, 8));
    float p = expf(acc - m);
    float s = p;
    for (int off = 1; off < 8; off <<= 1)
        s += __shfl_xor(s, off, 8);
    wout[(size_t)row * EE + e] = p / s;
}

// ---------------- old 128x128 GEMM (router-hidden only, EPI 0) ----------------
__global__ __launch_bounds__(256)
void gemm_bt(const unsigned short* __restrict__ A, const unsigned short* __restrict__ Bt,
             void* __restrict__ C, const float* __restrict__ bias,
             int M, int N, int K, int lda, int ldb, int ldc)
{
    __shared__ __align__(16) unsigned short As[BM * BK];
    __shared__ __align__(16) unsigned short Bs[BN * BK];

    const int tid  = threadIdx.x;
    const int lane = tid & 63;
    const int wave = tid >> 6;
    const int wm   = (wave >> 1) << 6;
    const int wn   = (wave & 1) << 6;
    const int l16  = lane & 15;
    const int lhi  = lane >> 4;

    const long bm0 = (long)blockIdx.x * BM;
    const long bn0 = (long)blockIdx.y * BN;

    const char* aBase = (const char*)(A + bm0 * lda);
    const char* bBase = (const char*)(Bt + bn0 * ldb);

    const char* asrc[4];
    const char* bsrc[4];
#pragma unroll
    for (int r = 0; r < 4; ++r) {
        int o = r * 4096 + tid * 16;
        asrc[r] = aBase + (long)(o >> 7) * (long)(lda * 2) + (o & 127);
        bsrc[r] = bBase + (long)(o >> 7) * (long)(ldb * 2) + (o & 127);
    }

    f32x4 acc[4][4];
    const f32x4 zero = {0.f, 0.f, 0.f, 0.f};
#pragma unroll
    for (int i = 0; i < 4; ++i)
#pragma unroll
        for (int j = 0; j < 4; ++j)
            acc[i][j] = zero;

    const int kiters = K / BK;
    for (int it = 0; it < kiters; ++it) {
        __syncthreads();
#pragma unroll
        for (int r = 0; r < 4; ++r) {
            llds16((char*)As + r * 4096 + tid * 16, asrc[r]);
            llds16((char*)Bs + r * 4096 + tid * 16, bsrc[r]);
            asrc[r] += BK * 2;
            bsrc[r] += BK * 2;
        }
        __syncthreads();

#pragma unroll
        for (int kk = 0; kk < BK; kk += 32) {
            bf16x8 af[4], bfr[4];
#pragma unroll
            for (int mi = 0; mi < 4; ++mi)
                af[mi] = *(const bf16x8*)(As + (wm + mi * 16 + l16) * BK + kk + lhi * 8);
#pragma unroll
            for (int ni = 0; ni < 4; ++ni)
                bfr[ni] = *(const bf16x8*)(Bs + (wn + ni * 16 + l16) * BK + kk + lhi * 8);
#pragma unroll
            for (int mi = 0; mi < 4; ++mi)
#pragma unroll
                for (int ni = 0; ni < 4; ++ni)
                    acc[mi][ni] = __builtin_amdgcn_mfma_f32_16x16x32_bf16(
                        af[mi], bfr[ni], acc[mi][ni], 0, 0, 0);
        }
    }

#pragma unroll
    for (int mi = 0; mi < 4; ++mi) {
#pragma unroll
        for (int ni = 0; ni < 4; ++ni) {
            const long gn = bn0 + wn + ni * 16 + l16;
            float bv = bias[gn];
#pragma unroll
            for (int r = 0; r < 4; ++r) {
                const long gm = bm0 + wm + mi * 16 + lhi * 4 + r;
                float v = fmaxf(acc[mi][ni][r] + bv, 0.f);
                ((unsigned short*)C)[gm * ldc + gn] = f2bf(v);
            }
        }
    }
}

// ---------------- deep-pipelined 256xBN GEMM: per-khalf phases, counted vmcnt ----------------
// C[M,N] = A[M,K] * Bt[N,K]^T.  BM=256, BK=64 (two K-halves of 32), 512 threads = 8 waves (2Mx4N).
// LDS per buffer: A 2 khalf x 256x32, B 2 khalf x BNv x 32 (bf16). Double-buffered by tile parity.
// Stage groups: G(kh) = {A khalf (2 loads), B khalf (1 or 2 loads)} for the NEXT tile, issued at
// the kh0-phase (group kh0) and kh1-phase (group kh1). Waits:
//   boundary (kh0 phase): vmcnt(GL) retires next... i.e. current tile's kh0 group (issued 4
//   phases earlier); kh1 phase: vmcnt(GL) retires current tile's kh1 group. GL = loads/group.
//   Tail tile: kh1 phase uses vmcnt(0) (no group in flight behind it).
// Every vmcnt is followed by s_barrier => all waves' groups landed before any wave reads.
// Stages write only the idle buffer; readers of that buffer completed (lgkmcnt(0) before MFMA,
// before the barriers separating them from the stage issue).
// EPI 1: bf16( relu(acc+bias[n]) * wrow[m][n>>8] ) ; EPI 2: bf16(acc) ; EPI 3: f32(acc)
template<int BNv, int EPI>
__global__ __launch_bounds__(512, 2)
void gemm8p(const unsigned short* __restrict__ A, const unsigned short* __restrict__ Bt,
            void* __restrict__ C, const float* __restrict__ bias,
            const float* __restrict__ wrow,
            int K, int lda, int ldb, int ldc)
{
    constexpr int NCW = BNv / 4;     // per-wave cols (64 or 32)
    constexpr int NI  = NCW / 16;    // acc cols (4 or 2)
    constexpr int BH  = BNv * 32;    // B ushorts per khalf

    __shared__ __align__(16) unsigned short Asl[2][2 * 8192];
    __shared__ __align__(16) unsigned short Bsl[2][2 * BH];

    const int tid  = threadIdx.x;
    const int lane = tid & 63;
    const int wv   = tid >> 6;
    const int wr   = wv >> 2;        // 0..1
    const int wc   = wv & 3;         // 0..3
    const int l16  = lane & 15;
    const int lhi  = lane >> 4;

    const long bm0 = (long)blockIdx.x * 256;
    const long bn0 = (long)blockIdx.y * BNv;

    // staging sources: linear LDS dest (tid*16), pre-swizzled global src
    const int r0 = tid >> 2;                          // 0..127
    const int sg = (tid & 3) ^ ((r0 >> 1) & 3);       // swizzled 16B slot within 64B row
    const char* aS0 = (const char*)A + (bm0 + r0) * (long)lda * 2 + sg * 16;
    const char* aS1 = aS0 + 128 * (long)lda * 2;
    const char* bS0 = (const char*)Bt + (bn0 + r0) * (long)ldb * 2 + sg * 16;
    const char* bS1 = bS0 + 128 * (long)ldb * 2;      // only used when BNv==256

    // ds_read addressing (ushort idx), same involution on the 16B slot
    const int swzu = (lhi ^ ((l16 >> 1) & 3)) << 3;
    const int arow = (wr * 128 + l16) * 32 + swzu;    // + mi*512 + kh*8192
    const int brow = (wc * NCW + l16) * 32 + swzu;    // + ni*512 + kh*BH

    f32x4 acc[8][NI];
    const f32x4 zero = {0.f, 0.f, 0.f, 0.f};
#pragma unroll
    for (int i = 0; i < 8; ++i)
#pragma unroll
        for (int j = 0; j < NI; ++j)
            acc[i][j] = zero;

    auto stageA = [&](int c, int kh, long cb) {
        char* d = (char*)&Asl[c][kh * 8192] + tid * 16;
        llds16(d,        aS0 + cb + kh * 64);
        llds16(d + 8192, aS1 + cb + kh * 64);
    };
    auto stageB = [&](int c, int kh, long cb) {
        char* d = (char*)&Bsl[c][kh * BH] + tid * 16;
        llds16(d, bS0 + cb + kh * 64);
        if constexpr (BNv == 256) llds16(d + 8192, bS1 + cb + kh * 64);
    };

    // prologue: tile 0, group kh0 then group kh1
    stageA(0, 0, 0); stageB(0, 0, 0);
    stageA(0, 1, 0); stageB(0, 1, 0);

    const int nt = K / 64;
    for (int t = 0; t < nt; ++t) {
        const int c  = t & 1;
        const bool pf = (t + 1 < nt);
        const long nb = (long)(t + 1) * 128;

        bf16x8 aF[8], bF[2];

        // ===== phase: kh0, ni-half 0 (tile boundary) =====
        if constexpr (BNv == 256) asm volatile("s_waitcnt vmcnt(4)" ::: "memory");
        else                      asm volatile("s_waitcnt vmcnt(3)" ::: "memory");
        rawbar();
#pragma unroll
        for (int mi = 0; mi < 8; ++mi)
            aF[mi] = *(const bf16x8*)&Asl[c][arow + mi * 512];
        bF[0] = *(const bf16x8*)&Bsl[c][brow];
        bF[1] = *(const bf16x8*)&Bsl[c][brow + 512];
        if (pf) { stageA(c ^ 1, 0, nb); stageB(c ^ 1, 0, nb); }
        asm volatile("s_waitcnt lgkmcnt(0)" ::: "memory");
        __builtin_amdgcn_sched_barrier(0);
        __builtin_amdgcn_s_setprio(1);
#pragma unroll
        for (int mi = 0; mi < 8; ++mi) {
            acc[mi][0] = __builtin_amdgcn_mfma_f32_16x16x32_bf16(aF[mi], bF[0], acc[mi][0], 0, 0, 0);
            acc[mi][1] = __builtin_amdgcn_mfma_f32_16x16x32_bf16(aF[mi], bF[1], acc[mi][1], 0, 0, 0);
        }
        __builtin_amdgcn_s_setprio(0);

        // ===== phase: kh0, ni-half 1 (BNv==256 only) =====
        if constexpr (BNv == 256) {
            rawbar();
            bF[0] = *(const bf16x8*)&Bsl[c][brow + 1024];
            bF[1] = *(const bf16x8*)&Bsl[c][brow + 1536];
            asm volatile("s_waitcnt lgkmcnt(0)" ::: "memory");
            __builtin_amdgcn_sched_barrier(0);
            __builtin_amdgcn_s_setprio(1);
#pragma unroll
            for (int mi = 0; mi < 8; ++mi) {
                acc[mi][2] = __builtin_amdgcn_mfma_f32_16x16x32_bf16(aF[mi], bF[0], acc[mi][2], 0, 0, 0);
                acc[mi][3] = __builtin_amdgcn_mfma_f32_16x16x32_bf16(aF[mi], bF[1], acc[mi][3], 0, 0, 0);
            }
            __builtin_amdgcn_s_setprio(0);
        }

        // ===== phase: kh1, ni-half 0 =====
        if (pf) {
            if constexpr (BNv == 256) asm volatile("s_waitcnt vmcnt(4)" ::: "memory");
            else                      asm volatile("s_waitcnt vmcnt(3)" ::: "memory");
        } else {
            asm volatile("s_waitcnt vmcnt(0)" ::: "memory");
        }
        rawbar();
#pragma unroll
        for (int mi = 0; mi < 8; ++mi)
            aF[mi] = *(const bf16x8*)&Asl[c][8192 + arow + mi * 512];
        bF[0] = *(const bf16x8*)&Bsl[c][BH + brow];
        bF[1] = *(const bf16x8*)&Bsl[c][BH + brow + 512];
        if (pf) { stageA(c ^ 1, 1, nb); stageB(c ^ 1, 1, nb); }
        asm volatile("s_waitcnt lgkmcnt(0)" ::: "memory");
        __builtin_amdgcn_sched_barrier(0);
        __builtin_amdgcn_s_setprio(1);
#pragma unroll
        for (int mi = 0; mi < 8; ++mi) {
            acc[mi][0] = __builtin_amdgcn_mfma_f32_16x16x32_bf16(aF[mi], bF[0], acc[mi][0], 0, 0, 0);
            acc[mi][1] = __builtin_amdgcn_mfma_f32_16x16x32_bf16(aF[mi], bF[1], acc[mi][1], 0, 0, 0);
        }
        __builtin_amdgcn_s_setprio(0);

        // ===== phase: kh1, ni-half 1 (BNv==256 only) =====
        if constexpr (BNv == 256) {
            rawbar();
            bF[0] = *(const bf16x8*)&Bsl[c][BH + brow + 1024];
            bF[1] = *(const bf16x8*)&Bsl[c][BH + brow + 1536];
            asm volatile("s_waitcnt lgkmcnt(0)" ::: "memory");
            __builtin_amdgcn_sched_barrier(0);
            __builtin_amdgcn_s_setprio(1);
#pragma unroll
            for (int mi = 0; mi < 8; ++mi) {
                acc[mi][2] = __builtin_amdgcn_mfma_f32_16x16x32_bf16(aF[mi], bF[0], acc[mi][2], 0, 0, 0);
                acc[mi][3] = __builtin_amdgcn_mfma_f32_16x16x32_bf16(aF[mi], bF[1], acc[mi][3], 0, 0, 0);
            }
            __builtin_amdgcn_s_setprio(0);
        }
    }

    // epilogue
#pragma unroll
    for (int mi = 0; mi < 8; ++mi) {
#pragma unroll
        for (int ni = 0; ni < NI; ++ni) {
            const long gn = bn0 + wc * NCW + ni * 16 + l16;
            float bv = 0.f;
            if (EPI == 1) bv = bias[gn];
#pragma unroll
            for (int r = 0; r < 4; ++r) {
                const long gm = bm0 + wr * 128 + mi * 16 + lhi * 4 + r;
                float v = acc[mi][ni][r];
                if (EPI == 1) {
                    v = fmaxf(v + bv, 0.f) * wrow[gm * 8 + (int)(gn >> 8)];
                    ((unsigned short*)C)[gm * (long)ldc + gn] = f2bf(v);
                } else if (EPI == 2) {
                    ((unsigned short*)C)[gm * (long)ldc + gn] = f2bf(v);
                } else {
                    ((float*)C)[gm * (long)ldc + gn] = v;
                }
            }
        }
    }
}

// ---------------- launch ----------------

extern "C" void kernel_launch(void* const* d_in, const int* in_sizes, int n_in,
                              void* d_out, int out_size, void* d_ws, size_t ws_size,
                              hipStream_t stream) {
    (void)in_sizes; (void)n_in; (void)out_size; (void)ws_size;
    const float* x   = (const float*)d_in[0];
    const float* rw1 = (const float*)d_in[1];
    const float* rb1 = (const float*)d_in[2];
    const float* rw2 = (const float*)d_in[3];
    const float* rb2 = (const float*)d_in[4];
    const float* ew1 = (const float*)d_in[5];
    const float* eb1 = (const float*)d_in[6];
    const float* ew2 = (const float*)d_in[7];
    const float* eb2 = (const float*)d_in[8];

    char* ws = (char*)d_ws;
    unsigned short* xb   = (unsigned short*)(ws);                 // 16,777,216 B
    unsigned short* rh   = (unsigned short*)(ws + 16777216);      //  2,097,152 B
    float*          wbuf = (float*)         (ws + 18874368);      //    262,144 B
    unsigned short* Hb   = (unsigned short*)(ws + 19136512);      // 34,603,008 B
    unsigned short* rw1t = (unsigned short*)(ws + 53739520);      //    262,144 B
    unsigned short* W1t  = (unsigned short*)(ws + 54001664);      //  4,194,304 B
    unsigned short* W2t  = (unsigned short*)(ws + 58195968);      //  4,325,376 B

    cvt_x<<<8192, 256, 0, stream>>>(x, xb);

    for (int l = 0; l < 3; ++l) {
        prep_rw1<<<512, 256, 0, stream>>>(rw1 + (size_t)l * DD * RHH, rw1t);
        prep_w1 <<<8192, 256, 0, stream>>>(ew1 + (size_t)l * EE * DD * EHH, W1t);
        prep_w2 <<<8448, 256, 0, stream>>>(ew2 + (size_t)l * EE * EHH * DD,
                                           eb2 + (size_t)l * EE * DD, W2t);

        // router hidden: rh = relu(x @ rw1 + rb1)  [8192,128]
        gemm_bt<<<dim3(64, 1), 256, 0, stream>>>(xb, rw1t, rh,
                                                 rb1 + l * RHH,
                                                 BB, RHH, DD, DD, DD, RHH);
        // softmax router weights
        router2<<<256, 256, 0, stream>>>(rh, rw2 + (size_t)l * RHH * EE,
                                         rb2 + l * EE, wbuf);
        // append w columns (+zero pad) to Hb
        fill_wcols<<<2048, 256, 0, stream>>>(wbuf, Hb);
        // H' = relu(x @ W1 + b1) * w   [8192, 2048] (stride 2112)
        gemm8p<256, 1><<<dim3(32, 8), 512, 0, stream>>>(xb, W1t, Hb,
                                                        eb1 + (size_t)l * NE1, wbuf,
                                                        DD, DD, DD, KX);
        // out = H' @ W2ext   (bias folded via K-extension)
        if (l < 2)
            gemm8p<128, 2><<<dim3(32, 8), 512, 0, stream>>>(Hb, W2t, xb, nullptr, nullptr,
                                                            KX, KX, KX, DD);
        else
            gemm8p<128, 3><<<dim3(32, 8), 512, 0, stream>>>(Hb, W2t, d_out, nullptr, nullptr,
                                                            KX, KX, KX, DD);
    }
}

// Round 4
// 320.111 us; speedup vs baseline: 1.5292x; 1.2663x over previous
//
#include <hip/hip_runtime.h>
#include <stdint.h>

#define BB   8192
#define DD   1024
#define EE   8
#define RHH  128
#define EHH  256
#define NE1  2048        // E*EH
#define KX   2112        // NE1 + 64 (8 bias cols + 56 zero pad), %64==0

using f32x4  = __attribute__((ext_vector_type(4))) float;
using bf16x8 = __attribute__((ext_vector_type(8))) __bf16;

__device__ __forceinline__ unsigned short f2bf(float f) {
    union { float f; uint32_t u; } v; v.f = f;
    uint32_t u = v.u;
    uint32_t r = (u + 0x7FFFu + ((u >> 16) & 1u)) >> 16;
    return (unsigned short)r;
}
__device__ __forceinline__ float bf2f(unsigned short h) {
    union { uint32_t u; float f; } v; v.u = ((uint32_t)h) << 16;
    return v.f;
}

__device__ __forceinline__ void llds16(void* l, const void* g) {
    __builtin_amdgcn_global_load_lds(
        (const __attribute__((address_space(1))) uint32_t*)g,
        (__attribute__((address_space(3))) uint32_t*)l, 16, 0, 0);
}

__device__ __forceinline__ void rawbar() {
    asm volatile("" ::: "memory");
    __builtin_amdgcn_s_barrier();
    asm volatile("" ::: "memory");
}

template<int N> __device__ __forceinline__ void vmwait() {
    asm volatile("s_waitcnt vmcnt(%0)" :: "n"(N) : "memory");
}

// ---------------- prep bodies ----------------

__device__ __forceinline__ void prep_body(int pbid, int tid,
    const float* __restrict__ rw1, const float* __restrict__ ew1,
    const float* __restrict__ ew2, const float* __restrict__ eb2,
    unsigned short* __restrict__ rw1t, unsigned short* __restrict__ W1t,
    unsigned short* __restrict__ W2t)
{
    if (pbid < 512) {                       // rw1t[h][d] = rw1[d][h]  (128x1024)
        int o = pbid * 256 + tid;
        int h = o >> 10, d = o & 1023;
        rw1t[o] = f2bf(rw1[d * RHH + h]);
    } else if (pbid < 8704) {               // W1t[n][k] = ew1[e][k][h], n=e*256+h
        int o = (pbid - 512) * 256 + tid;
        int n = o >> 10, k = o & 1023;
        int e = n >> 8, hh = n & 255;
        W1t[o] = f2bf(ew1[((e << 10) + k) * 256 + hh]);
    } else {                                // W2t[d][np] with bias rows + zero pad
        int o = (pbid - 8704) * 256 + tid;  // up to 1024*2112
        int d = o / KX;
        int np = o - d * KX;
        float v;
        if (np < NE1)            v = ew2[np * DD + d];
        else if (np < NE1 + EE)  v = eb2[(np - NE1) * DD + d];
        else                     v = 0.0f;
        W2t[o] = f2bf(v);
    }
}

// mega0: x->bf16 cvt (blocks [0,2048)), Hb zero-pads (blocks [2048,3840)),
//        level-0 prep (blocks [3840,20992))
__global__ __launch_bounds__(256) void mega0(
    const float* __restrict__ x, unsigned short* __restrict__ xb,
    unsigned short* __restrict__ Hb,
    const float* __restrict__ rw1, const float* __restrict__ ew1,
    const float* __restrict__ ew2, const float* __restrict__ eb2,
    unsigned short* __restrict__ rw1t, unsigned short* __restrict__ W1t,
    unsigned short* __restrict__ W2t)
{
    const int bid = blockIdx.x, tid = threadIdx.x;
    if (bid < 2048) {
        size_t idx = (size_t)bid * 256 + tid;      // 524288 threads * 16 elems
        const float* p = x + idx * 16;
        uint32_t w[8];
#pragma unroll
        for (int j = 0; j < 8; ++j) {
            f32x4 v; // two pairs per j? read 2 floats
            (void)v;
            w[j] = (uint32_t)f2bf(p[2 * j]) | ((uint32_t)f2bf(p[2 * j + 1]) << 16);
        }
        uint32_t* o = (uint32_t*)(xb + idx * 16);
        *(uint4*)(o)     = make_uint4(w[0], w[1], w[2], w[3]);
        *(uint4*)(o + 4) = make_uint4(w[4], w[5], w[6], w[7]);
    } else if (bid < 3840) {
        int idx = (bid - 2048) * 256 + tid;        // 8192*56
        int row = idx / 56, j = idx - row * 56;
        Hb[(size_t)row * KX + NE1 + EE + j] = 0;
    } else {
        prep_body(bid - 3840, tid, rw1, ew1, ew2, eb2, rw1t, W1t, W2t);
    }
}

__global__ __launch_bounds__(256) void prep_all(
    const float* __restrict__ rw1, const float* __restrict__ ew1,
    const float* __restrict__ ew2, const float* __restrict__ eb2,
    unsigned short* __restrict__ rw1t, unsigned short* __restrict__ W1t,
    unsigned short* __restrict__ W2t)
{
    prep_body(blockIdx.x, threadIdx.x, rw1, ew1, ew2, eb2, rw1t, W1t, W2t);
}

// ---------------- fused router: rh = relu(x@rw1+b1); w = softmax(rh@rw2+b2) ----------------
// grid 128 blocks x 512 threads. Block handles 64 rows. 8 waves = 2 k-groups x 4 row-quarters.
// K split: group g handles k in [g*512, (g+1)*512), 16 BK=32 tiles, 3-buf counted-vmcnt pipeline.
// Tail: g1 waves dump raw acc to LDS, g0 adds + bias + relu -> rhs f32[64][132];
// 512 threads do the 128x8 matvec; 64 threads softmax; writes wbuf f32 + Hb bf16 w-cols.
__global__ __launch_bounds__(512, 2) void router_fused(
    const unsigned short* __restrict__ xb, const unsigned short* __restrict__ rw1t,
    const float* __restrict__ rw2, const float* __restrict__ rb1,
    const float* __restrict__ rb2, float* __restrict__ wbuf,
    unsigned short* __restrict__ Hb)
{
    __shared__ __align__(16) char SR[73728];   // 3 bufs x (xs 8KB + ws 16KB); tail: rhs+lg

    const int tid = threadIdx.x;
    const int lane = tid & 63, wv = tid >> 6;
    const int g = wv >> 2, wq = wv & 3;
    const int l16 = lane & 15, lhi = lane >> 4;
    const long m0 = (long)blockIdx.x * 64;

    const int r0 = tid >> 2, sl = tid & 3;
    const int sg = sl ^ ((r0 >> 1) & 3);

    // stage sources
    const int xrow = (tid >> 2) & 63, xkg = tid >> 8;
    const char* xsrc = (const char*)xb + (m0 + xrow) * 2048 + xkg * 1024 + sg * 16;
    const char* wsrc = (const char*)rw1t + (long)r0 * 2048 + sg * 16;   // + j*1024

    f32x4 acc[8];
    const f32x4 zero = {0.f, 0.f, 0.f, 0.f};
#pragma unroll
    for (int i = 0; i < 8; ++i) acc[i] = zero;

    auto stage = [&](int buf, int t) {
        char* base = SR + buf * 24576;
        llds16(base + tid * 16, xsrc + t * 64);
        llds16(base + 8192 + tid * 16, wsrc + t * 64);
        llds16(base + 16384 + tid * 16, wsrc + 1024 + t * 64);
    };

    stage(0, 0); stage(1, 1);

    const int swz = (l16 >> 1) & 3;
    const int aoff = g * 2048 + (wq * 16 + l16) * 32 + ((lhi ^ swz) << 3);
    const int boff = 4096 + g * 4096 + l16 * 32 + ((lhi ^ swz) << 3);

    int cb = 0, sb = 2;
    for (int t = 0; t < 16; ++t) {
        if (t < 15) vmwait<3>(); else vmwait<0>();
        rawbar();
        const unsigned short* bufp = (const unsigned short*)(SR + cb * 24576);
        bf16x8 aF = *(const bf16x8*)&bufp[aoff];
        bf16x8 bF[8];
#pragma unroll
        for (int ni = 0; ni < 8; ++ni)
            bF[ni] = *(const bf16x8*)&bufp[boff + ni * 512];
        if (t + 2 < 16) stage(sb, t + 2);
        __builtin_amdgcn_s_setprio(1);
#pragma unroll
        for (int ni = 0; ni < 8; ++ni)
            acc[ni] = __builtin_amdgcn_mfma_f32_16x16x32_bf16(aF, bF[ni], acc[ni], 0, 0, 0);
        __builtin_amdgcn_s_setprio(0);
        cb = (cb + 1 == 3) ? 0 : cb + 1;
        sb = (sb + 1 == 3) ? 0 : sb + 1;
    }

    rawbar();   // all reads done before SR reuse

    float* rhs = (float*)SR;                     // [64][132]
    float* lg  = (float*)(SR + 64 * 132 * 4);    // [64][9]

    if (g == 1) {
#pragma unroll
        for (int ni = 0; ni < 8; ++ni)
#pragma unroll
            for (int rr = 0; rr < 4; ++rr)
                rhs[(wq * 16 + lhi * 4 + rr) * 132 + ni * 16 + l16] = acc[ni][rr];
    }
    rawbar();
    if (g == 0) {
#pragma unroll
        for (int ni = 0; ni < 8; ++ni) {
            float bv = rb1[ni * 16 + l16];
#pragma unroll
            for (int rr = 0; rr < 4; ++rr) {
                int row = wq * 16 + lhi * 4 + rr, col = ni * 16 + l16;
                float v = acc[ni][rr] + rhs[row * 132 + col] + bv;
                rhs[row * 132 + col] = fmaxf(v, 0.f);
            }
        }
    }
    rawbar();

    {   // matvec: thread -> (row, e)
        const int row = tid & 63, e = tid >> 6;
        float a2 = rb2[e];
        for (int h = 0; h < 128; ++h)
            a2 += rhs[row * 132 + h] * rw2[h * 8 + e];
        lg[row * 9 + e] = a2;
    }
    rawbar();

    if (tid < 64) {
        const int row = tid;
        float l[8], m = -1e30f;
#pragma unroll
        for (int e = 0; e < 8; ++e) { l[e] = lg[row * 9 + e]; m = fmaxf(m, l[e]); }
        float s = 0.f;
#pragma unroll
        for (int e = 0; e < 8; ++e) { l[e] = expf(l[e] - m); s += l[e]; }
        float inv = 1.f / s;
        const long gr = m0 + row;
#pragma unroll
        for (int e = 0; e < 8; ++e) {
            float w = l[e] * inv;
            wbuf[gr * 8 + e] = w;
            Hb[gr * KX + NE1 + e] = f2bf(w);
        }
    }
}

// ---------------- deep-pipelined GEMM: C[M,N] = A[M,K] * Bt[N,K]^T ----------------
// BM=256, 512 threads = 8 waves (WM x WN). NBUF-deep LDS rotation, stage distance SD=NBUF-1,
// ONE barrier + ONE counted vmcnt per K-tile (never 0 mid-loop). Ledger: entering tile t,
// outstanding loads = tiles t..t+SD-1 (LPT each); vmcnt(LPT*(SD-1)) retires tile t for this
// wave; barrier => for all waves. Stage of tile t+SD (buf (t-1)%NBUF) issues after barrier(t);
// its readers finished in tile t-1 before crossing barrier(t) -> safe for any wave drift.
// All of tile t's ds_reads batched post-barrier; compiler inserts partial lgkmcnt between
// MFMA clusters. XOR-swizzled 16B slots (involution on gload source + ds_read addr).
// EPI 1: bf16(relu(acc+bias[n])*wrow[m][n>>8]); EPI 2: bf16(acc); EPI 3: f32(acc)
template<int BNv, int BKv, int NBUF, int WNv, int EPI>
__global__ __launch_bounds__(512, 2)
void gemmT(const unsigned short* __restrict__ A, const unsigned short* __restrict__ Bt,
           void* __restrict__ C, const float* __restrict__ bias,
           const float* __restrict__ wrow,
           int K, int lda, int ldb, int ldc)
{
    constexpr int KH  = BKv / 32;
    constexpr int WMv = 8 / WNv;
    constexpr int MR  = 256 / WMv;
    constexpr int NC  = BNv / WNv;
    constexpr int MI  = MR / 16;
    constexpr int NI  = NC / 16;
    constexpr int NCH = 16 / MI;          // ni per MFMA cluster
    constexpr int ALP = 2;                // A loads per kh-region (256 rows)
    constexpr int BLP = (BNv * 64) / 8192;
    constexpr int LPT = KH * (ALP + BLP);
    constexpr int SD  = NBUF - 1;
    constexpr int AKH = 256 * 32;         // ushorts per A kh-region
    constexpr int BKH = BNv * 32;

    __shared__ __align__(16) unsigned short As[NBUF * KH * AKH];
    __shared__ __align__(16) unsigned short Bs[NBUF * KH * BKH];

    const int tid = threadIdx.x;
    const int lane = tid & 63, wv = tid >> 6;
    const int wr = wv / WNv, wc = wv % WNv;
    const int l16 = lane & 15, lhi = lane >> 4;
    const long bm0 = (long)blockIdx.x * 256;
    const long bn0 = (long)blockIdx.y * BNv;

    const int r0 = tid >> 2, sl = tid & 3;
    const int sg = sl ^ ((r0 >> 1) & 3);

    const char* aSrc[ALP];
    const char* bSrc[BLP];
#pragma unroll
    for (int a = 0; a < ALP; ++a)
        aSrc[a] = (const char*)A + (bm0 + a * 128 + r0) * (long)lda * 2 + sg * 16;
#pragma unroll
    for (int b = 0; b < BLP; ++b)
        bSrc[b] = (const char*)Bt + (bn0 + b * 128 + r0) * (long)ldb * 2 + sg * 16;

    f32x4 acc[MI][NI];
    const f32x4 zero = {0.f, 0.f, 0.f, 0.f};
#pragma unroll
    for (int i = 0; i < MI; ++i)
#pragma unroll
        for (int j = 0; j < NI; ++j)
            acc[i][j] = zero;

    auto stage = [&](int buf, int t) {
        const int cbyte = t * (BKv * 2);
#pragma unroll
        for (int kh = 0; kh < KH; ++kh) {
            char* ad = (char*)As + ((buf * KH + kh) * AKH) * 2 + tid * 16;
            char* bd = (char*)Bs + ((buf * KH + kh) * BKH) * 2 + tid * 16;
#pragma unroll
            for (int a = 0; a < ALP; ++a)
                llds16(ad + a * 8192, aSrc[a] + cbyte + kh * 64);
#pragma unroll
            for (int b = 0; b < BLP; ++b)
                llds16(bd + b * 8192, bSrc[b] + cbyte + kh * 64);
        }
    };

    const int nt = K / BKv;
#pragma unroll
    for (int p = 0; p < SD; ++p) stage(p, p);

    const int swz = (l16 >> 1) & 3;
    const int aoff = (wr * MR + l16) * 32 + ((lhi ^ swz) << 3);
    const int boff = (wc * NC + l16) * 32 + ((lhi ^ swz) << 3);

    int cb = 0, sb = SD % NBUF;
    for (int t = 0; t < nt; ++t) {
        const int rem = nt - 1 - t;
        if (rem >= SD - 1) vmwait<LPT * (SD - 1)>();
        else if constexpr (SD >= 3) {
            if (rem == 1) vmwait<LPT>(); else vmwait<0>();
        } else vmwait<0>();
        rawbar();

        bf16x8 aF[KH][MI], bF[KH][NI];
#pragma unroll
        for (int kh = 0; kh < KH; ++kh) {
            const unsigned short* ap = &As[(cb * KH + kh) * AKH];
            const unsigned short* bp = &Bs[(cb * KH + kh) * BKH];
#pragma unroll
            for (int mi = 0; mi < MI; ++mi)
                aF[kh][mi] = *(const bf16x8*)&ap[aoff + mi * 512];
#pragma unroll
            for (int ni = 0; ni < NI; ++ni)
                bF[kh][ni] = *(const bf16x8*)&bp[boff + ni * 512];
        }

        if (t + SD < nt) stage(sb, t + SD);

#pragma unroll
        for (int kh = 0; kh < KH; ++kh) {
#pragma unroll
            for (int nc0 = 0; nc0 < NI; nc0 += NCH) {
                __builtin_amdgcn_s_setprio(1);
#pragma unroll
                for (int mi = 0; mi < MI; ++mi)
#pragma unroll
                    for (int nj = 0; nj < NCH; ++nj)
                        acc[mi][nc0 + nj] = __builtin_amdgcn_mfma_f32_16x16x32_bf16(
                            aF[kh][mi], bF[kh][nc0 + nj], acc[mi][nc0 + nj], 0, 0, 0);
                __builtin_amdgcn_s_setprio(0);
            }
        }

        cb = (cb + 1 == NBUF) ? 0 : cb + 1;
        sb = (sb + 1 == NBUF) ? 0 : sb + 1;
    }

    // epilogue
#pragma unroll
    for (int mi = 0; mi < MI; ++mi) {
#pragma unroll
        for (int ni = 0; ni < NI; ++ni) {
            const long gn = bn0 + wc * NC + ni * 16 + l16;
            float bv = 0.f;
            if (EPI == 1) bv = bias[gn];
#pragma unroll
            for (int rr = 0; rr < 4; ++rr) {
                const long gm = bm0 + wr * MR + mi * 16 + lhi * 4 + rr;
                float v = acc[mi][ni][rr];
                if (EPI == 1) {
                    v = fmaxf(v + bv, 0.f) * wrow[gm * 8 + (int)(gn >> 8)];
                    ((unsigned short*)C)[gm * (long)ldc + gn] = f2bf(v);
                } else if (EPI == 2) {
                    ((unsigned short*)C)[gm * (long)ldc + gn] = f2bf(v);
                } else {
                    ((float*)C)[gm * (long)ldc + gn] = v;
                }
            }
        }
    }
}

// ---------------- launch ----------------

extern "C" void kernel_launch(void* const* d_in, const int* in_sizes, int n_in,
                              void* d_out, int out_size, void* d_ws, size_t ws_size,
                              hipStream_t stream) {
    (void)in_sizes; (void)n_in; (void)out_size; (void)ws_size;
    const float* x   = (const float*)d_in[0];
    const float* rw1 = (const float*)d_in[1];
    const float* rb1 = (const float*)d_in[2];
    const float* rw2 = (const float*)d_in[3];
    const float* rb2 = (const float*)d_in[4];
    const float* ew1 = (const float*)d_in[5];
    const float* eb1 = (const float*)d_in[6];
    const float* ew2 = (const float*)d_in[7];
    const float* eb2 = (const float*)d_in[8];

    char* ws = (char*)d_ws;
    unsigned short* xb   = (unsigned short*)(ws);                 // 16,777,216 B
    float*          wbuf = (float*)         (ws + 16777216);      //    262,144 B
    unsigned short* Hb   = (unsigned short*)(ws + 17039360);      // 34,603,008 B
    unsigned short* rw1t = (unsigned short*)(ws + 51642368);      //    262,144 B
    unsigned short* W1t  = (unsigned short*)(ws + 51904512);      //  4,194,304 B
    unsigned short* W2t  = (unsigned short*)(ws + 56098816);      //  4,325,376 B
    // total 60,424,192 B

    // cvt + Hb zero-pads + level-0 prep, one dispatch
    mega0<<<20992, 256, 0, stream>>>(x, xb, Hb, rw1, ew1, ew2, eb2, rw1t, W1t, W2t);

    for (int l = 0; l < 3; ++l) {
        if (l > 0)
            prep_all<<<17152, 256, 0, stream>>>(rw1 + (size_t)l * DD * RHH,
                                                ew1 + (size_t)l * EE * DD * EHH,
                                                ew2 + (size_t)l * EE * EHH * DD,
                                                eb2 + (size_t)l * EE * DD,
                                                rw1t, W1t, W2t);

        router_fused<<<128, 512, 0, stream>>>(xb, rw1t,
                                              rw2 + (size_t)l * RHH * EE,
                                              rb1 + (size_t)l * RHH,
                                              rb2 + (size_t)l * EE, wbuf, Hb);

        // H' = relu(x @ W1 + b1) * w   [8192, 2048] (stride KX)
        gemmT<256, 32, 4, 4, 1><<<dim3(32, 8), 512, 0, stream>>>(
            xb, W1t, Hb, eb1 + (size_t)l * NE1, wbuf, DD, DD, DD, KX);

        // out = H' @ W2ext (bias folded via K-extension)
        if (l < 2)
            gemmT<128, 64, 3, 2, 2><<<dim3(32, 8), 512, 0, stream>>>(
                Hb, W2t, xb, nullptr, nullptr, KX, KX, KX, DD);
        else
            gemmT<128, 64, 3, 2, 3><<<dim3(32, 8), 512, 0, stream>>>(
                Hb, W2t, d_out, nullptr, nullptr, KX, KX, KX, DD);
    }
}